// Round 1
// baseline (408.834 us; speedup 1.0000x reference)
//
#include <hip/hip_runtime.h>
#include <hip/hip_bf16.h>

// ---------- types ----------
typedef short s8v __attribute__((ext_vector_type(8)));   // 8 x bf16 (4 VGPRs)
typedef float f4v __attribute__((ext_vector_type(4)));   // 4 x f32 accumulator

#define NUM_EMBEDS 8192
#define EMBED_DIM  256
#define BATCH      16
#define HW         1024                 // 32*32
#define NVEC       (BATCH * HW)         // 16384 vectors
#define OUT0_ELEMS (BATCH * EMBED_DIM * HW)  // 4194304

static __device__ __forceinline__ unsigned short f32_to_bf16_rne(float f) {
    unsigned int u = __float_as_uint(f);
    unsigned int r = u + 0x7FFFu + ((u >> 16) & 1u);
    return (unsigned short)(r >> 16);
}

// ---------- kernel 1: transpose x [16][256][1024] f32 -> xb [16384][256] bf16 ----------
__global__ void k_transpose_x(const float* __restrict__ x, unsigned short* __restrict__ xb,
                              float* __restrict__ loss) {
    __shared__ float t[32][33];
    const int tx = threadIdx.x;          // 0..31
    const int ty = threadIdx.y;          // 0..7
    const int hw0 = blockIdx.x * 32;
    const int c0  = blockIdx.y * 32;
    const int b   = blockIdx.z;
    if (blockIdx.x == 0 && blockIdx.y == 0 && blockIdx.z == 0 && tx == 0 && ty == 0)
        *loss = 0.0f;
    #pragma unroll
    for (int i = 0; i < 4; ++i) {
        const int c = c0 + ty + i * 8;
        t[ty + i * 8][tx] = x[((b * EMBED_DIM + c) << 10) + hw0 + tx];
    }
    __syncthreads();
    #pragma unroll
    for (int i = 0; i < 4; ++i) {
        const int hw = hw0 + ty + i * 8;
        const int n = b * HW + hw;
        xb[n * EMBED_DIM + c0 + tx] = f32_to_bf16_rne(t[tx][ty + i * 8]);
    }
}

// ---------- kernel 2: codebook f32 -> bf16 + e2 ----------
__global__ void k_convert_cb(const float* __restrict__ cb, unsigned short* __restrict__ eb,
                             float* __restrict__ e2) {
    const int e = blockIdx.x;
    const int tid = threadIdx.x;      // 0..255
    const float v = cb[e * EMBED_DIM + tid];
    eb[e * EMBED_DIM + tid] = f32_to_bf16_rne(v);
    float s = v * v;
    #pragma unroll
    for (int off = 32; off > 0; off >>= 1) s += __shfl_down(s, off, 64);
    __shared__ float ls[4];
    const int lane = tid & 63, wid = tid >> 6;
    if (lane == 0) ls[wid] = s;
    __syncthreads();
    if (tid == 0) e2[e] = ls[0] + ls[1] + ls[2] + ls[3];
}

// ---------- kernel 3: fused GEMM + argmin ----------
// grid 256 blocks (64 rows each), 256 threads = 4 waves.
// wave w handles cols [nt*256 + w*64, +64) for nt in 0..31 (covers all 8192).
__global__ void __launch_bounds__(256)
k_argmin(const unsigned short* __restrict__ xb, const unsigned short* __restrict__ eb,
         const float* __restrict__ e2, int* __restrict__ idxout) {
    const int tid  = threadIdx.x;
    const int lane = tid & 63;
    const int wid  = tid >> 6;
    const int l15  = lane & 15;
    const int lg   = lane >> 4;          // 0..3
    const int row0 = blockIdx.x * 64;

    const unsigned short* aBase = xb + (size_t)(row0 + l15) * EMBED_DIM + lg * 8;
    const unsigned short* bBase = eb + (size_t)l15 * EMBED_DIM + lg * 8;

    float minv[4][4];
    int   mini[4][4];
    #pragma unroll
    for (int mr = 0; mr < 4; ++mr)
        #pragma unroll
        for (int r = 0; r < 4; ++r) { minv[mr][r] = 3.4e38f; mini[mr][r] = 0; }

    for (int nt = 0; nt < 32; ++nt) {
        const int col0 = nt * 256 + wid * 64;
        f4v acc[4][4];
        #pragma unroll
        for (int mr = 0; mr < 4; ++mr)
            #pragma unroll
            for (int nc = 0; nc < 4; ++nc)
                acc[mr][nc] = (f4v){0.f, 0.f, 0.f, 0.f};

        #pragma unroll
        for (int kk = 0; kk < 8; ++kk) {
            s8v a[4], b[4];
            #pragma unroll
            for (int mr = 0; mr < 4; ++mr)
                a[mr] = *reinterpret_cast<const s8v*>(aBase + mr * 16 * EMBED_DIM + kk * 32);
            #pragma unroll
            for (int nc = 0; nc < 4; ++nc)
                b[nc] = *reinterpret_cast<const s8v*>(bBase + (col0 + nc * 16) * EMBED_DIM + kk * 32);
            #pragma unroll
            for (int mr = 0; mr < 4; ++mr)
                #pragma unroll
                for (int nc = 0; nc < 4; ++nc)
                    acc[mr][nc] = __builtin_amdgcn_mfma_f32_16x16x32_bf16(a[mr], b[nc], acc[mr][nc], 0, 0, 0);
        }

        #pragma unroll
        for (int nc = 0; nc < 4; ++nc) {
            const int col = col0 + nc * 16 + l15;
            const float ev = e2[col];
            #pragma unroll
            for (int mr = 0; mr < 4; ++mr)
                #pragma unroll
                for (int r = 0; r < 4; ++r) {
                    const float score = fmaf(-2.0f, acc[mr][nc][r], ev);
                    if (score < minv[mr][r]) { minv[mr][r] = score; mini[mr][r] = col; }
                }
        }
    }

    // reduce across the 16 lanes that share a row group (same lg, different l15)
    __shared__ float lds_min[4][64];
    __shared__ int   lds_idx[4][64];
    #pragma unroll
    for (int mr = 0; mr < 4; ++mr)
        #pragma unroll
        for (int r = 0; r < 4; ++r) {
            float v = minv[mr][r]; int i = mini[mr][r];
            #pragma unroll
            for (int m = 1; m <= 8; m <<= 1) {
                const float v2 = __shfl_xor(v, m, 64);
                const int   i2 = __shfl_xor(i, m, 64);
                if (v2 < v || (v2 == v && i2 < i)) { v = v2; i = i2; }
            }
            if (l15 == 0) {
                const int rl = mr * 16 + lg * 4 + r;
                lds_min[wid][rl] = v;
                lds_idx[wid][rl] = i;
            }
        }
    __syncthreads();
    if (tid < 64) {
        float v = lds_min[0][tid]; int i = lds_idx[0][tid];
        #pragma unroll
        for (int w = 1; w < 4; ++w) {
            const float v2 = lds_min[w][tid];
            const int   i2 = lds_idx[w][tid];
            if (v2 < v || (v2 == v && i2 < i)) { v = v2; i = i2; }
        }
        idxout[row0 + tid] = i;
    }
}

// ---------- kernel 4: gather + straight-through output + loss partial ----------
__global__ void k_gather_loss(const float* __restrict__ x, const float* __restrict__ cb,
                              const int* __restrict__ idx, float* __restrict__ out,
                              float* __restrict__ loss) {
    const int tid = threadIdx.x;
    const int id = blockIdx.x * 256 + tid;           // [b][c][hw] linear
    const int hw = id & 1023;
    const int bc = id >> 10;
    const int c = bc & 255;
    const int b = bc >> 8;
    const int n = (b << 10) + hw;
    const int e = idx[n];
    const float q = cb[e * EMBED_DIM + c];
    const float xv = x[id];
    out[id] = xv + (q - xv);                          // straight-through == q
    float d = q - xv;
    float s = d * d;
    #pragma unroll
    for (int off = 32; off > 0; off >>= 1) s += __shfl_down(s, off, 64);
    __shared__ float ls[4];
    const int lane = tid & 63, wid = tid >> 6;
    if (lane == 0) ls[wid] = s;
    __syncthreads();
    if (tid == 0) atomicAdd(loss, ls[0] + ls[1] + ls[2] + ls[3]);
}

// ---------- kernel 5: finalize loss ----------
__global__ void k_finalize(const float* __restrict__ loss, float* __restrict__ out) {
    // vq_loss = beta*mse + mse = 1.25 * sum / OUT0_ELEMS
    out[OUT0_ELEMS] = loss[0] * (1.25f / (float)OUT0_ELEMS);
}

extern "C" void kernel_launch(void* const* d_in, const int* in_sizes, int n_in,
                              void* d_out, int out_size, void* d_ws, size_t ws_size,
                              hipStream_t stream) {
    const float* x  = (const float*)d_in[0];
    const float* cb = (const float*)d_in[1];
    float* out = (float*)d_out;

    char* ws = (char*)d_ws;
    unsigned short* xb = (unsigned short*)ws;                         // 8 MB
    unsigned short* eb = (unsigned short*)(ws + 8388608);             // 4 MB
    float* e2   = (float*)(ws + 12582912);                            // 32 KB
    int*   idx  = (int*)(ws + 12615680);                              // 64 KB
    float* loss = (float*)(ws + 12681216);                            // 4 B

    k_transpose_x<<<dim3(32, 8, 16), dim3(32, 8, 1), 0, stream>>>(x, xb, loss);
    k_convert_cb<<<dim3(NUM_EMBEDS), dim3(256), 0, stream>>>(cb, eb, e2);
    k_argmin<<<dim3(NVEC / 64), dim3(256), 0, stream>>>(xb, eb, e2, idx);
    k_gather_loss<<<dim3(OUT0_ELEMS / 256), dim3(256), 0, stream>>>(x, cb, idx, out, loss);
    k_finalize<<<dim3(1), dim3(1), 0, stream>>>(loss, out);
}

// Round 2
// 227.899 us; speedup vs baseline: 1.7939x; 1.7939x over previous
//
#include <hip/hip_runtime.h>
#include <hip/hip_bf16.h>

// ---------- types ----------
typedef short s8v __attribute__((ext_vector_type(8)));   // 8 x bf16 (4 VGPRs)
typedef float f4v __attribute__((ext_vector_type(4)));   // 4 x f32 accumulator

#define NUM_EMBEDS 8192
#define EMBED_DIM  256
#define BATCH      16
#define HW         1024                 // 32*32
#define NVEC       (BATCH * HW)         // 16384 vectors
#define OUT0_ELEMS (BATCH * EMBED_DIM * HW)  // 4194304
#define NSPLIT     4                     // column splits for k_argmin

static __device__ __forceinline__ unsigned short f32_to_bf16_rne(float f) {
    unsigned int u = __float_as_uint(f);
    unsigned int r = u + 0x7FFFu + ((u >> 16) & 1u);
    return (unsigned short)(r >> 16);
}

// ---------- kernel 1: transpose x [16][256][1024] f32 -> xb [16384][256] bf16 ----------
__global__ void k_transpose_x(const float* __restrict__ x, unsigned short* __restrict__ xb,
                              float* __restrict__ loss) {
    __shared__ float t[32][33];
    const int tx = threadIdx.x;          // 0..31
    const int ty = threadIdx.y;          // 0..7
    const int hw0 = blockIdx.x * 32;
    const int c0  = blockIdx.y * 32;
    const int b   = blockIdx.z;
    if (blockIdx.x == 0 && blockIdx.y == 0 && blockIdx.z == 0 && tx == 0 && ty == 0)
        *loss = 0.0f;
    #pragma unroll
    for (int i = 0; i < 4; ++i) {
        const int c = c0 + ty + i * 8;
        t[ty + i * 8][tx] = x[((b * EMBED_DIM + c) << 10) + hw0 + tx];
    }
    __syncthreads();
    #pragma unroll
    for (int i = 0; i < 4; ++i) {
        const int hw = hw0 + ty + i * 8;
        const int n = b * HW + hw;
        xb[n * EMBED_DIM + c0 + tx] = f32_to_bf16_rne(t[tx][ty + i * 8]);
    }
}

// ---------- kernel 2: codebook f32 -> bf16 + e2 ----------
__global__ void k_convert_cb(const float* __restrict__ cb, unsigned short* __restrict__ eb,
                             float* __restrict__ e2) {
    const int e = blockIdx.x;
    const int tid = threadIdx.x;      // 0..255
    const float v = cb[e * EMBED_DIM + tid];
    eb[e * EMBED_DIM + tid] = f32_to_bf16_rne(v);
    float s = v * v;
    #pragma unroll
    for (int off = 32; off > 0; off >>= 1) s += __shfl_down(s, off, 64);
    __shared__ float ls[4];
    const int lane = tid & 63, wid = tid >> 6;
    if (lane == 0) ls[wid] = s;
    __syncthreads();
    if (tid == 0) e2[e] = ls[0] + ls[1] + ls[2] + ls[3];
}

// ---------- kernel 3: fused GEMM + argmin (column-split for occupancy) ----------
// grid (256 row-blocks, NSPLIT col-splits), 256 threads = 4 waves.
// Block (rb, s): rows [rb*64, +64), cols [s*2048, +2048).
// Wave w handles cols s*2048 + nt*256 + w*64 for nt in 0..7.
__global__ void __launch_bounds__(256)
k_argmin(const unsigned short* __restrict__ xb, const unsigned short* __restrict__ eb,
         const float* __restrict__ e2, float* __restrict__ pv, int* __restrict__ pi) {
    const int tid  = threadIdx.x;
    const int lane = tid & 63;
    const int wid  = tid >> 6;
    const int l15  = lane & 15;
    const int lg   = lane >> 4;          // 0..3
    const int row0 = blockIdx.x * 64;
    const int s    = blockIdx.y;

    const unsigned short* aBase = xb + (size_t)(row0 + l15) * EMBED_DIM + lg * 8;
    const unsigned short* bBase = eb + (size_t)l15 * EMBED_DIM + lg * 8;

    float minv[4][4];
    int   mini[4][4];
    #pragma unroll
    for (int mr = 0; mr < 4; ++mr)
        #pragma unroll
        for (int r = 0; r < 4; ++r) { minv[mr][r] = 3.4e38f; mini[mr][r] = 0; }

    for (int nt = 0; nt < 8; ++nt) {
        const int col0 = s * 2048 + nt * 256 + wid * 64;
        f4v acc[4][4];
        #pragma unroll
        for (int mr = 0; mr < 4; ++mr)
            #pragma unroll
            for (int nc = 0; nc < 4; ++nc)
                acc[mr][nc] = (f4v){0.f, 0.f, 0.f, 0.f};

        #pragma unroll
        for (int kk = 0; kk < 8; ++kk) {
            s8v a[4], b[4];
            #pragma unroll
            for (int mr = 0; mr < 4; ++mr)
                a[mr] = *reinterpret_cast<const s8v*>(aBase + mr * 16 * EMBED_DIM + kk * 32);
            #pragma unroll
            for (int nc = 0; nc < 4; ++nc)
                b[nc] = *reinterpret_cast<const s8v*>(bBase + (col0 + nc * 16) * EMBED_DIM + kk * 32);
            #pragma unroll
            for (int mr = 0; mr < 4; ++mr)
                #pragma unroll
                for (int nc = 0; nc < 4; ++nc)
                    acc[mr][nc] = __builtin_amdgcn_mfma_f32_16x16x32_bf16(a[mr], b[nc], acc[mr][nc], 0, 0, 0);
        }

        #pragma unroll
        for (int nc = 0; nc < 4; ++nc) {
            const int col = col0 + nc * 16 + l15;
            const float ev = e2[col];
            #pragma unroll
            for (int mr = 0; mr < 4; ++mr)
                #pragma unroll
                for (int r = 0; r < 4; ++r) {
                    const float score = fmaf(-2.0f, acc[mr][nc][r], ev);
                    if (score < minv[mr][r]) { minv[mr][r] = score; mini[mr][r] = col; }
                }
        }
    }

    // reduce across the 16 lanes sharing a row group; then across waves via LDS
    __shared__ float lds_min[4][64];
    __shared__ int   lds_idx[4][64];
    #pragma unroll
    for (int mr = 0; mr < 4; ++mr)
        #pragma unroll
        for (int r = 0; r < 4; ++r) {
            float v = minv[mr][r]; int i = mini[mr][r];
            #pragma unroll
            for (int m = 1; m <= 8; m <<= 1) {
                const float v2 = __shfl_xor(v, m, 64);
                const int   i2 = __shfl_xor(i, m, 64);
                if (v2 < v || (v2 == v && i2 < i)) { v = v2; i = i2; }
            }
            if (l15 == 0) {
                const int rl = mr * 16 + lg * 4 + r;
                lds_min[wid][rl] = v;
                lds_idx[wid][rl] = i;
            }
        }
    __syncthreads();
    if (tid < 64) {
        float v = lds_min[0][tid]; int i = lds_idx[0][tid];
        #pragma unroll
        for (int w = 1; w < 4; ++w) {
            const float v2 = lds_min[w][tid];
            const int   i2 = lds_idx[w][tid];
            if (v2 < v || (v2 == v && i2 < i)) { v = v2; i = i2; }
        }
        pv[s * NVEC + row0 + tid] = v;
        pi[s * NVEC + row0 + tid] = i;
    }
}

// ---------- kernel 3b: merge column-split partials ----------
__global__ void k_merge(const float* __restrict__ pv, const int* __restrict__ pi,
                        int* __restrict__ idxout) {
    const int row = blockIdx.x * 256 + threadIdx.x;
    float v = pv[row]; int i = pi[row];
    #pragma unroll
    for (int s = 1; s < NSPLIT; ++s) {
        const float v2 = pv[s * NVEC + row];
        const int   i2 = pi[s * NVEC + row];
        if (v2 < v || (v2 == v && i2 < i)) { v = v2; i = i2; }
    }
    idxout[row] = i;
}

// ---------- kernel 4: gather + straight-through output + loss partial ----------
// block = (b, 32-hw tile). Codebook rows loaded coalesced (e uniform per block),
// staged in LDS [32][257], written out coalesced along hw.
__global__ void __launch_bounds__(256)
k_gather_loss(const float* __restrict__ x, const float* __restrict__ cb,
              const int* __restrict__ idx, float* __restrict__ out,
              float* __restrict__ loss) {
    __shared__ float q[32][257];
    __shared__ int e_s[32];
    const int tid = threadIdx.x;
    const int hw0 = (blockIdx.x & 31) * 32;
    const int b   = blockIdx.x >> 5;
    const int n0  = (b << 10) + hw0;
    if (tid < 32) e_s[tid] = idx[n0 + tid];
    __syncthreads();
    #pragma unroll 8
    for (int r = 0; r < 32; ++r)
        q[r][tid] = cb[(size_t)e_s[r] * EMBED_DIM + tid];
    __syncthreads();
    const int tx = tid & 31;    // hw offset within tile
    const int ty = tid >> 5;    // 0..7  (channel group)
    float sum = 0.f;
    #pragma unroll
    for (int i = 0; i < 32; ++i) {
        const int c = ty * 32 + i;
        const float qv = q[tx][c];
        const int o = ((b * EMBED_DIM + c) << 10) + hw0 + tx;
        const float xv = x[o];
        out[o] = qv;                      // straight-through value == quantized
        const float d = qv - xv;
        sum = fmaf(d, d, sum);
    }
    #pragma unroll
    for (int off = 32; off > 0; off >>= 1) sum += __shfl_down(sum, off, 64);
    __shared__ float ls[4];
    const int lane = tid & 63, wid = tid >> 6;
    if (lane == 0) ls[wid] = sum;
    __syncthreads();
    if (tid == 0) atomicAdd(loss, ls[0] + ls[1] + ls[2] + ls[3]);
}

// ---------- kernel 5: finalize loss ----------
__global__ void k_finalize(const float* __restrict__ loss, float* __restrict__ out) {
    // vq_loss = beta*mse + mse = 1.25 * sum / OUT0_ELEMS
    out[OUT0_ELEMS] = loss[0] * (1.25f / (float)OUT0_ELEMS);
}

extern "C" void kernel_launch(void* const* d_in, const int* in_sizes, int n_in,
                              void* d_out, int out_size, void* d_ws, size_t ws_size,
                              hipStream_t stream) {
    const float* x  = (const float*)d_in[0];
    const float* cb = (const float*)d_in[1];
    float* out = (float*)d_out;

    char* ws = (char*)d_ws;
    unsigned short* xb = (unsigned short*)ws;                         // 8 MB
    unsigned short* eb = (unsigned short*)(ws + 8388608);             // 4 MB
    float* e2   = (float*)(ws + 12582912);                            // 32 KB
    int*   idx  = (int*)(ws + 12615680);                              // 64 KB
    float* loss = (float*)(ws + 12681216);                            // 4 B (pad to 512)
    float* pv   = (float*)(ws + 12681728);                            // 4*16384*4 = 256 KB
    int*   pi   = (int*)(ws + 12943872);                              // 256 KB  (ends ~13.2 MB)

    k_transpose_x<<<dim3(32, 8, 16), dim3(32, 8, 1), 0, stream>>>(x, xb, loss);
    k_convert_cb<<<dim3(NUM_EMBEDS), dim3(256), 0, stream>>>(cb, eb, e2);
    k_argmin<<<dim3(NVEC / 64, NSPLIT), dim3(256), 0, stream>>>(xb, eb, e2, pv, pi);
    k_merge<<<dim3(NVEC / 256), dim3(256), 0, stream>>>(pv, pi, idx);
    k_gather_loss<<<dim3(512), dim3(256), 0, stream>>>(x, cb, idx, out, loss);
    k_finalize<<<dim3(1), dim3(1), 0, stream>>>(loss, out);
}